// Round 12
// baseline (20.400 us; speedup 1.0000x reference)
//
#include <hip/hip_runtime.h>

// Problem constants (fixed by the reference)
#define BB   4096
#define NN   16
#define AA   8
#define DIN  128
#define H1C  64
#define DPC  64
#define DZC  64

#define GENV 8     // envs per block in compute kernel (wave w <-> env w)
#define NTHR 512   // 8 waves

// Collapsed reference (round-0 derivation; verified passing R1/R3..R11):
//   agg   = mean_n obs[b,n,:]                      [128]
//   h     = relu(agg @ W1 + b1)                    [64]
//   (p eliminated:)  u = Wfc @ (Wattn[:64]+Wattn[64:]);  v1 = W2 @ u;  v2 = W2 @ Wv[:64]
//   logit = h.v1 + b2.u ;  wgt = sigmoid(leaky_relu(logit))   -> entire w output
//   c     = h.v2 + b2.Wv[:64] + bv
//   dv[j] = (pi[b,j]-act[b,j]) . Wv[64:72]         [16]
//   Sv    = sum(pi.v) - wgt * sum((pi-act).v)
//   x[b,d,j] = c + (Sv + wgt*dv[j]) / 16           (independent of d)

__device__ __forceinline__ float lane_bcast(float v, int lane) {
    return __int_as_float(__builtin_amdgcn_readlane(__float_as_int(v), lane));
}

// ============ K1: pure-streaming obs mean (R6/R8-exact serial-sum tree) ======
// wave <-> env; lane l owns columns 2l, 2l+1. 16 x 512B coalesced loads/wave,
// one 512B store. No barriers, no cross-lane ops -> fill-kernel-like BW.
__global__ __launch_bounds__(256, 4)
void agg_kernel(const float* __restrict__ obs,   // [B*N, 128]
                float* __restrict__ agg)         // [B, 128] (d_ws)
{
    const int tid = threadIdx.x;
    const int l   = tid & 63;
    const int w   = tid >> 6;
    const int e   = blockIdx.x * 4 + w;

    const float2* o2 = reinterpret_cast<const float2*>(obs) + (size_t)e * (NN * DIN / 2);
    float2 ov[NN];
    #pragma unroll
    for (int r = 0; r < NN; ++r) ov[r] = o2[r * 64 + l];

    float sx = 0.0f, sy = 0.0f;
    #pragma unroll
    for (int r = 0; r < NN; ++r) { sx += ov[r].x; sy += ov[r].y; }
    const float inv = 1.0f / 16.0f;
    reinterpret_cast<float2*>(agg)[(size_t)e * 64 + l] = make_float2(sx * inv, sy * inv);
}

// ============ K2: R8 compute kernel, obs phase replaced by agg row load ======
__global__ __launch_bounds__(NTHR, 4)
void critic_kernel(const float* __restrict__ agg,      // [B, 128] (d_ws)
                   const float* __restrict__ policies, // [B*N, 8]
                   const float* __restrict__ actions,  // [B*N, 8]
                   const float* __restrict__ W1,       // [128,64]
                   const float* __restrict__ b1,       // [64]
                   const float* __restrict__ W2,       // [64,64]
                   const float* __restrict__ b2,       // [64]
                   const float* __restrict__ Wfc,      // [64,64]
                   const float* __restrict__ Wattn,    // [128]
                   const float* __restrict__ Wv,       // [72]
                   const float* __restrict__ bv,       // [1]
                   float* __restrict__ out_x,          // [B*N*N]
                   float* __restrict__ out_w)          // [B*N*N]
{
    // W1 transposed tile, XOR-swizzled at float4 granularity (R8-passing):
    //   [c][4*d4..4*d4+3] lives at sW1T4[c*32 + (d4 ^ (c&7))] -> conflict-free b128.
    __shared__ float4 sW1T4[H1C * 32];  // 32 KB
    __shared__ float sV1[H1C];
    __shared__ float sV2[H1C];
    __shared__ float sS[2];             // tb2u, tb2w
    __shared__ float sDv[GENV][16];     // 512 B
    __shared__ float sWsum[DZC];        // wave-7 scratch
    __shared__ float sWv64[DPC];
    __shared__ float sU[DPC];           // ~34.6 KB total -> 2 blocks/CU

    const int tid = threadIdx.x;
    const int l   = tid & 63;
    const int w   = tid >> 6;                    // wave id == local env id
    const int e   = blockIdx.x * GENV + w;       // this wave's env

    // ---- agg row load: lane l holds agg[2l] (ax), agg[2l+1] (ay) — exactly
    //      the register state R8's phase-1 produced. ----
    const float2 agv = reinterpret_cast<const float2*>(agg)[(size_t)e * 64 + l];
    const float ax = agv.x, ay = agv.y;

    // ---- stage W1 transposed+swizzled (R8 form: thread=(col c,grp), 4 quads) ----
    {
        const int c   = tid & 63;
        const int grp = tid >> 6;
        #pragma unroll
        for (int i = 0; i < 4; ++i) {
            const int d0 = 4 * (i * 8 + grp);     // 0,4,...,124
            const float w0  = W1[(d0 + 0) * H1C + c];
            const float w1_ = W1[(d0 + 1) * H1C + c];
            const float w2_ = W1[(d0 + 2) * H1C + c];
            const float w3_ = W1[(d0 + 3) * H1C + c];
            sW1T4[c * 32 + ((d0 >> 2) ^ (c & 7))] = make_float4(w0, w1_, w2_, w3_);
        }
    }

    // ---- pol/act loads (early issue) ----
    const float* Pb = policies + (size_t)e * (NN * AA);
    const float* Ab = actions  + (size_t)e * (NN * AA);
    const float pv0 = Pb[l], pv1 = Pb[64 + l];
    const float av0 = Ab[l], av1 = Ab[64 + l];

    // ---- small params ----
    const float b1v = b1[l];
    const float va  = Wv[64 + (l & 7)];
    const float bvv = bv[0];

    // ---- wave 7: env-independent u/v1/v2 (R8-passing form, same-wave LDS) ----
    if (w == 7) {
        const float b2v  = b2[l];
        const float wsum = Wattn[l] + Wattn[DZC + l];
        const float wvv  = Wv[l];
        sWsum[l] = wsum;
        sWv64[l] = wvv;

        float u = 0.0f;
        {
            const float4* WfcR = reinterpret_cast<const float4*>(Wfc) + (size_t)l * (DZC / 4);
            const float4* ws4  = reinterpret_cast<const float4*>(sWsum);
            #pragma unroll
            for (int j4 = 0; j4 < DZC / 4; ++j4) {
                const float4 wq = WfcR[j4];
                const float4 s  = ws4[j4];          // LDS broadcast (same-wave RAW)
                u = fmaf(wq.x, s.x, u); u = fmaf(wq.y, s.y, u);
                u = fmaf(wq.z, s.z, u); u = fmaf(wq.w, s.w, u);
            }
        }
        sU[l] = u;
        float v1 = 0.0f, v2 = 0.0f;
        {
            const float4* W2R = reinterpret_cast<const float4*>(W2) + (size_t)l * (DPC / 4);
            const float4* su4 = reinterpret_cast<const float4*>(sU);
            const float4* sv4 = reinterpret_cast<const float4*>(sWv64);
            #pragma unroll
            for (int j4 = 0; j4 < DPC / 4; ++j4) {
                const float4 wq = W2R[j4];
                const float4 a  = su4[j4];
                const float4 b  = sv4[j4];
                v1 = fmaf(wq.x, a.x, v1); v1 = fmaf(wq.y, a.y, v1);
                v1 = fmaf(wq.z, a.z, v1); v1 = fmaf(wq.w, a.w, v1);
                v2 = fmaf(wq.x, b.x, v2); v2 = fmaf(wq.y, b.y, v2);
                v2 = fmaf(wq.z, b.z, v2); v2 = fmaf(wq.w, b.w, v2);
            }
        }
        float tb2u_ = b2v * u;
        float tb2w_ = b2v * wvv;
        #pragma unroll
        for (int m = 32; m >= 1; m >>= 1) {
            tb2u_ += __shfl_xor(tb2u_, m);
            tb2w_ += __shfl_xor(tb2w_, m);
        }
        sV1[l] = v1;
        sV2[l] = v2;
        if (l == 0) { sS[0] = tb2u_; sS[1] = tb2w_; }
    }

    // ---- pol/act shuffle trees (R3/R8 order; pre-barrier) ----
    float fqv, fpv;
    {
        float q0 = (pv0 - av0) * va;   // -> dv[l>>3]
        float q1 = (pv1 - av1) * va;   // -> dv[8+(l>>3)]
        float fq = q0 + q1;
        float fp = (pv0 + pv1) * va;
        #pragma unroll
        for (int m = 1; m <= 4; m <<= 1) { q0 += __shfl_xor(q0, m); q1 += __shfl_xor(q1, m); }
        #pragma unroll
        for (int m = 32; m >= 1; m >>= 1) { fq += __shfl_xor(fq, m); fp += __shfl_xor(fp, m); }
        fqv = fq; fpv = fp;
        if ((l & 7) == 0) { sDv[w][l >> 3] = q0; sDv[w][8 + (l >> 3)] = q1; }
    }

    __syncthreads();   // sW1T4 (cross-wave) + sV1/sV2/sS visible (the ONLY barrier)

    // ---- mv1: h = relu(agg @ W1 + b1); R8-exact chains & readlane mapping ----
    float a0 = b1v, a1 = 0.0f, a2 = 0.0f, a3 = 0.0f;
    #pragma unroll
    for (int d4 = 0; d4 < DIN / 4; ++d4) {
        const float4 w4 = sW1T4[l * 32 + (d4 ^ (l & 7))];
        a0 = fmaf(lane_bcast(ax, 2 * d4),     w4.x, a0);   // agg[4d4]
        a1 = fmaf(lane_bcast(ay, 2 * d4),     w4.y, a1);   // agg[4d4+1]
        a2 = fmaf(lane_bcast(ax, 2 * d4 + 1), w4.z, a2);   // agg[4d4+2]
        a3 = fmaf(lane_bcast(ay, 2 * d4 + 1), w4.w, a3);   // agg[4d4+3]
    }
    const float h = fmaxf((a0 + a1) + (a2 + a3), 0.0f);

    // ---- per-env scalars (R7/R8 trees) ----
    const float v1l  = sV1[l];
    const float v2l  = sV2[l];
    const float tb2u = sS[0];
    const float tb2w = sS[1];

    float t0 = h * v1l;
    float t1 = h * v2l;
    #pragma unroll
    for (int m = 32; m >= 1; m >>= 1) {
        t0 += __shfl_xor(t0, m);
        t1 += __shfl_xor(t1, m);
    }
    const float logit = t0 + tb2u;
    const float eV  = (logit > 0.0f) ? logit : 0.01f * logit;   // leaky slope 0.01
    const float wgt = 1.0f / (1.0f + expf(-eV));
    const float c   = t1 + tb2w + bvv;
    const float Sv  = fpv - wgt * fqv;

    // ---- outputs: 16 distinct x per env, broadcast over d; w scalar ----
    const float invN = 1.0f / 16.0f;
    const int j0 = (4 * l) & 15;          // 0,4,8,12; j0..j0+3 never wrap
    float4 xo, wo;
    xo.x = fmaf(wgt, sDv[w][j0 + 0], Sv) * invN + c;
    xo.y = fmaf(wgt, sDv[w][j0 + 1], Sv) * invN + c;
    xo.z = fmaf(wgt, sDv[w][j0 + 2], Sv) * invN + c;
    xo.w = fmaf(wgt, sDv[w][j0 + 3], Sv) * invN + c;
    wo.x = wo.y = wo.z = wo.w = wgt;

    const size_t base = (size_t)e * (NN * NN) + 4 * l;
    *reinterpret_cast<float4*>(out_x + base) = xo;
    *reinterpret_cast<float4*>(out_w + base) = wo;
}

extern "C" void kernel_launch(void* const* d_in, const int* in_sizes, int n_in,
                              void* d_out, int out_size, void* d_ws, size_t ws_size,
                              hipStream_t stream) {
    const float* obs      = (const float*)d_in[0];
    const float* policies = (const float*)d_in[1];
    const float* actions  = (const float*)d_in[2];
    const float* W1       = (const float*)d_in[3];
    const float* b1       = (const float*)d_in[4];
    const float* W2       = (const float*)d_in[5];
    const float* b2       = (const float*)d_in[6];
    const float* Wfc      = (const float*)d_in[7];
    const float* Wattn    = (const float*)d_in[8];
    const float* Wv       = (const float*)d_in[9];
    const float* bv       = (const float*)d_in[10];

    float* out_x = (float*)d_out;                    // [B*N*N] = 1048576
    float* out_w = out_x + (size_t)BB * NN * NN;     // second tuple element
    float* agg   = (float*)d_ws;                     // [B,128] f32 = 2 MB scratch

    agg_kernel<<<BB / 4, 256, 0, stream>>>(obs, agg);
    critic_kernel<<<BB / GENV, NTHR, 0, stream>>>(agg, policies, actions,
                                                  W1, b1, W2, b2, Wfc, Wattn, Wv, bv,
                                                  out_x, out_w);
}

// Round 13
// 19.245 us; speedup vs baseline: 1.0600x; 1.0600x over previous
//
#include <hip/hip_runtime.h>

// Problem constants (fixed by the reference)
#define BB   4096
#define NN   16
#define AA   8
#define DIN  128
#define H1C  64
#define DPC  64
#define DZC  64

#define GENV 16    // envs per block; wave w owns envs 2w, 2w+1 (pipelined)
#define NTHR 512   // 8 waves; grid = 256 (1 block/CU)

// Collapsed reference (round-0 derivation; verified passing R1/R3..R12):
//   agg   = mean_n obs[b,n,:]                      [128]
//   h     = relu(agg @ W1 + b1)                    [64]
//   (p eliminated:)  u = Wfc @ (Wattn[:64]+Wattn[64:]);  v1 = W2 @ u;  v2 = W2 @ Wv[:64]
//   logit = h.v1 + b2.u ;  wgt = sigmoid(leaky_relu(logit))   -> entire w output
//   c     = h.v2 + b2.Wv[:64] + bv
//   dv[j] = (pi[b,j]-act[b,j]) . Wv[64:72]         [16]
//   Sv    = sum(pi.v) - wgt * sum((pi-act).v)
//   x[b,d,j] = c + (Sv + wgt*dv[j]) / 16           (independent of d)

__device__ __forceinline__ float lane_bcast(float v, int lane) {
    return __int_as_float(__builtin_amdgcn_readlane(__float_as_int(v), lane));
}

__global__ __launch_bounds__(NTHR, 2)
void critic_kernel(const float* __restrict__ obs,      // [B*N, 128]
                   const float* __restrict__ policies, // [B*N, 8]
                   const float* __restrict__ actions,  // [B*N, 8]
                   const float* __restrict__ W1,       // [128,64]
                   const float* __restrict__ b1,       // [64]
                   const float* __restrict__ W2,       // [64,64]
                   const float* __restrict__ b2,       // [64]
                   const float* __restrict__ Wfc,      // [64,64]
                   const float* __restrict__ Wattn,    // [128]
                   const float* __restrict__ Wv,       // [72]
                   const float* __restrict__ bv,       // [1]
                   float* __restrict__ out_x,          // [B*N*N]
                   float* __restrict__ out_w)          // [B*N*N]
{
    // W1 transposed tile, XOR-swizzled at float4 granularity (R8-passing):
    //   [c][4*d4..4*d4+3] lives at sW1T4[c*32 + (d4 ^ (c&7))] -> conflict-free b128.
    __shared__ float4 sW1T4[H1C * 32];  // 32 KB
    __shared__ float sV1[H1C];
    __shared__ float sV2[H1C];
    __shared__ float sS[2];             // tb2u, tb2w
    __shared__ float sDv[GENV][16];     // 1 KB
    __shared__ float sWsum[DZC];        // wave-7 scratch
    __shared__ float sWv64[DPC];
    __shared__ float sU[DPC];           // ~34.3 KB total

    const int tid = threadIdx.x;
    const int l   = tid & 63;
    const int w   = tid >> 6;                    // wave id 0..7
    const int leA = 2 * w;                       // this wave's two envs
    const int leB = 2 * w + 1;
    const int eA  = blockIdx.x * GENV + leA;
    const int eB  = blockIdx.x * GENV + leB;

    // ---- env A obs loads FIRST (R1/R9 float4 layout; oldest in vmcnt queue) ----
    const float4* o4A = reinterpret_cast<const float4*>(obs + (size_t)eA * NN * DIN);
    const float4* o4B = reinterpret_cast<const float4*>(obs + (size_t)eB * NN * DIN);
    float4 ovA[8];
    #pragma unroll
    for (int t = 0; t < 8; ++t) ovA[t] = o4A[t * 64 + l];

    // ---- stage W1 transposed+swizzled (R8 form: thread=(col c,grp), 4 quads) ----
    {
        const int c   = tid & 63;
        const int grp = tid >> 6;
        #pragma unroll
        for (int i = 0; i < 4; ++i) {
            const int d0 = 4 * (i * 8 + grp);     // 0,4,...,124
            const float w0  = W1[(d0 + 0) * H1C + c];
            const float w1_ = W1[(d0 + 1) * H1C + c];
            const float w2_ = W1[(d0 + 2) * H1C + c];
            const float w3_ = W1[(d0 + 3) * H1C + c];
            sW1T4[c * 32 + ((d0 >> 2) ^ (c & 7))] = make_float4(w0, w1_, w2_, w3_);
        }
    }

    // ---- pol/act loads, both envs ----
    const float* PbA = policies + (size_t)eA * (NN * AA);
    const float* AbA = actions  + (size_t)eA * (NN * AA);
    const float* PbB = policies + (size_t)eB * (NN * AA);
    const float* AbB = actions  + (size_t)eB * (NN * AA);
    const float pv0A = PbA[l], pv1A = PbA[64 + l], av0A = AbA[l], av1A = AbA[64 + l];
    const float pv0B = PbB[l], pv1B = PbB[64 + l], av0B = AbB[l], av1B = AbB[64 + l];

    // ---- small params ----
    const float b1v = b1[l];
    const float va  = Wv[64 + (l & 7)];
    const float bvv = bv[0];

    // ---- wave 7: env-independent u/v1/v2 (R8-passing form, same-wave LDS) ----
    if (w == 7) {
        const float b2v  = b2[l];
        const float wsum = Wattn[l] + Wattn[DZC + l];
        const float wvv  = Wv[l];
        sWsum[l] = wsum;
        sWv64[l] = wvv;

        float u = 0.0f;
        {
            const float4* WfcR = reinterpret_cast<const float4*>(Wfc) + (size_t)l * (DZC / 4);
            const float4* ws4  = reinterpret_cast<const float4*>(sWsum);
            #pragma unroll
            for (int j4 = 0; j4 < DZC / 4; ++j4) {
                const float4 wq = WfcR[j4];
                const float4 s  = ws4[j4];          // LDS broadcast (same-wave RAW)
                u = fmaf(wq.x, s.x, u); u = fmaf(wq.y, s.y, u);
                u = fmaf(wq.z, s.z, u); u = fmaf(wq.w, s.w, u);
            }
        }
        sU[l] = u;
        float v1 = 0.0f, v2 = 0.0f;
        {
            const float4* W2R = reinterpret_cast<const float4*>(W2) + (size_t)l * (DPC / 4);
            const float4* su4 = reinterpret_cast<const float4*>(sU);
            const float4* sv4 = reinterpret_cast<const float4*>(sWv64);
            #pragma unroll
            for (int j4 = 0; j4 < DPC / 4; ++j4) {
                const float4 wq = W2R[j4];
                const float4 a  = su4[j4];
                const float4 b  = sv4[j4];
                v1 = fmaf(wq.x, a.x, v1); v1 = fmaf(wq.y, a.y, v1);
                v1 = fmaf(wq.z, a.z, v1); v1 = fmaf(wq.w, a.w, v1);
                v2 = fmaf(wq.x, b.x, v2); v2 = fmaf(wq.y, b.y, v2);
                v2 = fmaf(wq.z, b.z, v2); v2 = fmaf(wq.w, b.w, v2);
            }
        }
        float tb2u_ = b2v * u;
        float tb2w_ = b2v * wvv;
        #pragma unroll
        for (int m = 32; m >= 1; m >>= 1) {
            tb2u_ += __shfl_xor(tb2u_, m);
            tb2w_ += __shfl_xor(tb2w_, m);
        }
        sV1[l] = v1;
        sV2[l] = v2;
        if (l == 0) { sS[0] = tb2u_; sS[1] = tb2w_; }
    }

    // ---- pol/act shuffle trees, A then B (R3/R8 order; pre-barrier) ----
    float fqA, fpA, fqB, fpB;
    {
        float q0 = (pv0A - av0A) * va;
        float q1 = (pv1A - av1A) * va;
        float fq = q0 + q1;
        float fp = (pv0A + pv1A) * va;
        #pragma unroll
        for (int m = 1; m <= 4; m <<= 1) { q0 += __shfl_xor(q0, m); q1 += __shfl_xor(q1, m); }
        #pragma unroll
        for (int m = 32; m >= 1; m >>= 1) { fq += __shfl_xor(fq, m); fp += __shfl_xor(fp, m); }
        fqA = fq; fpA = fp;
        if ((l & 7) == 0) { sDv[leA][l >> 3] = q0; sDv[leA][8 + (l >> 3)] = q1; }
    }
    {
        float q0 = (pv0B - av0B) * va;
        float q1 = (pv1B - av1B) * va;
        float fq = q0 + q1;
        float fp = (pv0B + pv1B) * va;
        #pragma unroll
        for (int m = 1; m <= 4; m <<= 1) { q0 += __shfl_xor(q0, m); q1 += __shfl_xor(q1, m); }
        #pragma unroll
        for (int m = 32; m >= 1; m >>= 1) { fq += __shfl_xor(fq, m); fp += __shfl_xor(fp, m); }
        fqB = fq; fpB = fp;
        if ((l & 7) == 0) { sDv[leB][l >> 3] = q0; sDv[leB][8 + (l >> 3)] = q1; }
    }

    // ---- env A obs mean PRE-barrier (R1/R9 tree; consumes only A's loads,
    //      which the upcoming barrier would drain anyway) ----
    const float invN = 1.0f / 16.0f;
    float4 agA;
    {
        float4 a = make_float4(0.f, 0.f, 0.f, 0.f);
        #pragma unroll
        for (int t = 0; t < 8; ++t) {
            a.x += ovA[t].x; a.y += ovA[t].y; a.z += ovA[t].z; a.w += ovA[t].w;
        }
        a.x += __shfl_xor(a.x, 32);
        a.y += __shfl_xor(a.y, 32);
        a.z += __shfl_xor(a.z, 32);
        a.w += __shfl_xor(a.w, 32);
        agA = make_float4(a.x * invN, a.y * invN, a.z * invN, a.w * invN);
    }

    __syncthreads();   // sW1T4 + sV1/sV2/sS visible; drains A-loads (consumed)

    // ---- issue env B obs loads NOW (post-barrier so the barrier's vmcnt(0)
    //      drain can't touch them); pin issue point against reordering. ----
    float4 ovB[8];
    #pragma unroll
    for (int t = 0; t < 8; ++t) ovB[t] = o4B[t * 64 + l];
    __builtin_amdgcn_sched_barrier(0);

    const float v1l  = sV1[l];
    const float v2l  = sV2[l];
    const float tb2u = sS[0];
    const float tb2w = sS[1];
    const int   j0   = (4 * l) & 15;       // 0,4,8,12; j0..j0+3 never wrap

    // ======== env A compute + store (runs while B's stream is in flight) ====
    {
        float a0 = b1v, a1 = 0.0f, a2 = 0.0f, a3 = 0.0f;
        #pragma unroll
        for (int d4 = 0; d4 < DIN / 4; ++d4) {
            const float4 w4 = sW1T4[l * 32 + (d4 ^ (l & 7))];
            a0 = fmaf(lane_bcast(agA.x, d4), w4.x, a0);   // agg[4d4]
            a1 = fmaf(lane_bcast(agA.y, d4), w4.y, a1);   // agg[4d4+1]
            a2 = fmaf(lane_bcast(agA.z, d4), w4.z, a2);   // agg[4d4+2]
            a3 = fmaf(lane_bcast(agA.w, d4), w4.w, a3);   // agg[4d4+3]
        }
        const float h = fmaxf((a0 + a1) + (a2 + a3), 0.0f);

        float t0 = h * v1l;
        float t1 = h * v2l;
        #pragma unroll
        for (int m = 32; m >= 1; m >>= 1) { t0 += __shfl_xor(t0, m); t1 += __shfl_xor(t1, m); }
        const float logit = t0 + tb2u;
        const float eV  = (logit > 0.0f) ? logit : 0.01f * logit;  // leaky slope 0.01
        const float wgt = 1.0f / (1.0f + expf(-eV));
        const float c   = t1 + tb2w + bvv;
        const float Sv  = fpA - wgt * fqA;

        float4 xo, wo;
        xo.x = fmaf(wgt, sDv[leA][j0 + 0], Sv) * invN + c;
        xo.y = fmaf(wgt, sDv[leA][j0 + 1], Sv) * invN + c;
        xo.z = fmaf(wgt, sDv[leA][j0 + 2], Sv) * invN + c;
        xo.w = fmaf(wgt, sDv[leA][j0 + 3], Sv) * invN + c;
        wo.x = wo.y = wo.z = wo.w = wgt;

        const size_t base = (size_t)eA * (NN * NN) + 4 * l;
        *reinterpret_cast<float4*>(out_x + base) = xo;
        *reinterpret_cast<float4*>(out_w + base) = wo;
    }

    // ======== env B: mean (waits B stream), compute + store ====
    {
        float4 a = make_float4(0.f, 0.f, 0.f, 0.f);
        #pragma unroll
        for (int t = 0; t < 8; ++t) {
            a.x += ovB[t].x; a.y += ovB[t].y; a.z += ovB[t].z; a.w += ovB[t].w;
        }
        a.x += __shfl_xor(a.x, 32);
        a.y += __shfl_xor(a.y, 32);
        a.z += __shfl_xor(a.z, 32);
        a.w += __shfl_xor(a.w, 32);
        const float4 agB = make_float4(a.x * invN, a.y * invN, a.z * invN, a.w * invN);

        float a0 = b1v, a1 = 0.0f, a2 = 0.0f, a3 = 0.0f;
        #pragma unroll
        for (int d4 = 0; d4 < DIN / 4; ++d4) {
            const float4 w4 = sW1T4[l * 32 + (d4 ^ (l & 7))];
            a0 = fmaf(lane_bcast(agB.x, d4), w4.x, a0);
            a1 = fmaf(lane_bcast(agB.y, d4), w4.y, a1);
            a2 = fmaf(lane_bcast(agB.z, d4), w4.z, a2);
            a3 = fmaf(lane_bcast(agB.w, d4), w4.w, a3);
        }
        const float h = fmaxf((a0 + a1) + (a2 + a3), 0.0f);

        float t0 = h * v1l;
        float t1 = h * v2l;
        #pragma unroll
        for (int m = 32; m >= 1; m >>= 1) { t0 += __shfl_xor(t0, m); t1 += __shfl_xor(t1, m); }
        const float logit = t0 + tb2u;
        const float eV  = (logit > 0.0f) ? logit : 0.01f * logit;
        const float wgt = 1.0f / (1.0f + expf(-eV));
        const float c   = t1 + tb2w + bvv;
        const float Sv  = fpB - wgt * fqB;

        float4 xo, wo;
        xo.x = fmaf(wgt, sDv[leB][j0 + 0], Sv) * invN + c;
        xo.y = fmaf(wgt, sDv[leB][j0 + 1], Sv) * invN + c;
        xo.z = fmaf(wgt, sDv[leB][j0 + 2], Sv) * invN + c;
        xo.w = fmaf(wgt, sDv[leB][j0 + 3], Sv) * invN + c;
        wo.x = wo.y = wo.z = wo.w = wgt;

        const size_t base = (size_t)eB * (NN * NN) + 4 * l;
        *reinterpret_cast<float4*>(out_x + base) = xo;
        *reinterpret_cast<float4*>(out_w + base) = wo;
    }
}

extern "C" void kernel_launch(void* const* d_in, const int* in_sizes, int n_in,
                              void* d_out, int out_size, void* d_ws, size_t ws_size,
                              hipStream_t stream) {
    const float* obs      = (const float*)d_in[0];
    const float* policies = (const float*)d_in[1];
    const float* actions  = (const float*)d_in[2];
    const float* W1       = (const float*)d_in[3];
    const float* b1       = (const float*)d_in[4];
    const float* W2       = (const float*)d_in[5];
    const float* b2       = (const float*)d_in[6];
    const float* Wfc      = (const float*)d_in[7];
    const float* Wattn    = (const float*)d_in[8];
    const float* Wv       = (const float*)d_in[9];
    const float* bv       = (const float*)d_in[10];

    float* out_x = (float*)d_out;                    // [B*N*N] = 1048576
    float* out_w = out_x + (size_t)BB * NN * NN;     // second tuple element

    critic_kernel<<<BB / GENV, NTHR, 0, stream>>>(obs, policies, actions,
                                                  W1, b1, W2, b2, Wfc, Wattn, Wv, bv,
                                                  out_x, out_w);
}

// Round 14
// 17.480 us; speedup vs baseline: 1.1670x; 1.1010x over previous
//
#include <hip/hip_runtime.h>

// Problem constants (fixed by the reference)
#define BB   4096
#define NN   16
#define AA   8
#define DIN  128
#define H1C  64
#define DPC  64
#define DZC  64

#define GENV 8     // envs per block == waves per block (wave w <-> env w)
#define NTHR 512   // 8 waves; grid = 512 = 2 blocks/CU (R8-proven geometry)

// Collapsed reference (round-0 derivation; verified passing R1/R3..R13):
//   agg   = mean_n obs[b,n,:]                      [128]
//   h     = relu(agg @ W1 + b1)                    [64]
//   (p eliminated:)  u = Wfc @ (Wattn[:64]+Wattn[64:]);  v1 = W2 @ u;  v2 = W2 @ Wv[:64]
//   logit = h.v1 + b2.u ;  wgt = sigmoid(leaky_relu(logit))   -> entire w output
//   c     = h.v2 + b2.Wv[:64] + bv
//   dv[j] = (pi[b,j]-act[b,j]) . Wv[64:72]         [16]
//   Sv    = sum(pi.v) - wgt * sum((pi-act).v)
//   x[b,d,j] = c + (Sv + wgt*dv[j]) / 16           (independent of d)
//
// Floor model (R14): memory 44.3 MB @ 6.3 TB/s = 7.0 us + launch/replay ~10 us
// = ~17 us; R8 measured 17.4. This round = R8 + R11's float4 obs path only.

__device__ __forceinline__ float lane_bcast(float v, int lane) {
    return __int_as_float(__builtin_amdgcn_readlane(__float_as_int(v), lane));
}

__global__ __launch_bounds__(NTHR, 4)
void critic_kernel(const float* __restrict__ obs,      // [B*N, 128]
                   const float* __restrict__ policies, // [B*N, 8]
                   const float* __restrict__ actions,  // [B*N, 8]
                   const float* __restrict__ W1,       // [128,64]
                   const float* __restrict__ b1,       // [64]
                   const float* __restrict__ W2,       // [64,64]
                   const float* __restrict__ b2,       // [64]
                   const float* __restrict__ Wfc,      // [64,64]
                   const float* __restrict__ Wattn,    // [128]
                   const float* __restrict__ Wv,       // [72]
                   const float* __restrict__ bv,       // [1]
                   float* __restrict__ out_x,          // [B*N*N]
                   float* __restrict__ out_w)          // [B*N*N]
{
    // W1 transposed tile, XOR-swizzled at float4 granularity (R8-passing):
    //   [c][4*d4..4*d4+3] lives at sW1T4[c*32 + (d4 ^ (c&7))] -> conflict-free b128.
    __shared__ float4 sW1T4[H1C * 32];  // 32 KB
    __shared__ float sV1[H1C];
    __shared__ float sV2[H1C];
    __shared__ float sS[2];             // tb2u, tb2w
    __shared__ float sDv[GENV][16];     // 512 B
    __shared__ float sWsum[DZC];        // wave-7 scratch
    __shared__ float sWv64[DPC];
    __shared__ float sU[DPC];           // ~34.6 KB total -> 2 blocks/CU

    const int tid = threadIdx.x;
    const int l   = tid & 63;
    const int w   = tid >> 6;                    // wave id == local env id
    const int e   = blockIdx.x * GENV + w;       // this wave's env

    // ---- obs loads: R11-verified float4 layout (8 x 1KB-per-wave instrs) ----
    const float4* o4 = reinterpret_cast<const float4*>(obs + (size_t)e * NN * DIN);
    float4 ov[8];
    #pragma unroll
    for (int t = 0; t < 8; ++t) ov[t] = o4[t * 64 + l];

    // ---- stage W1 transposed+swizzled (R8 form: thread=(col c,grp), 4 quads) ----
    {
        const int c   = tid & 63;
        const int grp = tid >> 6;
        #pragma unroll
        for (int i = 0; i < 4; ++i) {
            const int d0 = 4 * (i * 8 + grp);     // 0,4,...,124
            const float w0  = W1[(d0 + 0) * H1C + c];
            const float w1_ = W1[(d0 + 1) * H1C + c];
            const float w2_ = W1[(d0 + 2) * H1C + c];
            const float w3_ = W1[(d0 + 3) * H1C + c];
            sW1T4[c * 32 + ((d0 >> 2) ^ (c & 7))] = make_float4(w0, w1_, w2_, w3_);
        }
    }

    // ---- pol/act loads (early issue) ----
    const float* Pb = policies + (size_t)e * (NN * AA);
    const float* Ab = actions  + (size_t)e * (NN * AA);
    const float pv0 = Pb[l], pv1 = Pb[64 + l];
    const float av0 = Ab[l], av1 = Ab[64 + l];

    // ---- small params ----
    const float b1v = b1[l];
    const float va  = Wv[64 + (l & 7)];
    const float bvv = bv[0];

    // ---- wave 7: env-independent u/v1/v2 (R8-passing form, same-wave LDS) ----
    if (w == 7) {
        const float b2v  = b2[l];
        const float wsum = Wattn[l] + Wattn[DZC + l];
        const float wvv  = Wv[l];
        sWsum[l] = wsum;
        sWv64[l] = wvv;

        float u = 0.0f;
        {
            const float4* WfcR = reinterpret_cast<const float4*>(Wfc) + (size_t)l * (DZC / 4);
            const float4* ws4  = reinterpret_cast<const float4*>(sWsum);
            #pragma unroll
            for (int j4 = 0; j4 < DZC / 4; ++j4) {
                const float4 wq = WfcR[j4];
                const float4 s  = ws4[j4];          // LDS broadcast (same-wave RAW)
                u = fmaf(wq.x, s.x, u); u = fmaf(wq.y, s.y, u);
                u = fmaf(wq.z, s.z, u); u = fmaf(wq.w, s.w, u);
            }
        }
        sU[l] = u;
        float v1 = 0.0f, v2 = 0.0f;
        {
            const float4* W2R = reinterpret_cast<const float4*>(W2) + (size_t)l * (DPC / 4);
            const float4* su4 = reinterpret_cast<const float4*>(sU);
            const float4* sv4 = reinterpret_cast<const float4*>(sWv64);
            #pragma unroll
            for (int j4 = 0; j4 < DPC / 4; ++j4) {
                const float4 wq = W2R[j4];
                const float4 a  = su4[j4];
                const float4 b  = sv4[j4];
                v1 = fmaf(wq.x, a.x, v1); v1 = fmaf(wq.y, a.y, v1);
                v1 = fmaf(wq.z, a.z, v1); v1 = fmaf(wq.w, a.w, v1);
                v2 = fmaf(wq.x, b.x, v2); v2 = fmaf(wq.y, b.y, v2);
                v2 = fmaf(wq.z, b.z, v2); v2 = fmaf(wq.w, b.w, v2);
            }
        }
        float tb2u_ = b2v * u;
        float tb2w_ = b2v * wvv;
        #pragma unroll
        for (int m = 32; m >= 1; m >>= 1) {
            tb2u_ += __shfl_xor(tb2u_, m);
            tb2w_ += __shfl_xor(tb2w_, m);
        }
        sV1[l] = v1;
        sV2[l] = v2;
        if (l == 0) { sS[0] = tb2u_; sS[1] = tb2w_; }
    }

    // ---- pol/act shuffle trees (R3/R8 order; pre-barrier) ----
    float fqv, fpv;
    {
        float q0 = (pv0 - av0) * va;   // -> dv[l>>3]
        float q1 = (pv1 - av1) * va;   // -> dv[8+(l>>3)]
        float fq = q0 + q1;
        float fp = (pv0 + pv1) * va;
        #pragma unroll
        for (int m = 1; m <= 4; m <<= 1) { q0 += __shfl_xor(q0, m); q1 += __shfl_xor(q1, m); }
        #pragma unroll
        for (int m = 32; m >= 1; m >>= 1) { fq += __shfl_xor(fq, m); fp += __shfl_xor(fp, m); }
        fqv = fq; fpv = fp;
        if ((l & 7) == 0) { sDv[w][l >> 3] = q0; sDv[w][8 + (l >> 3)] = q1; }
    }

    // ---- obs mean (R1/R11 tree: zero-init + 8 adds, xor-32, /16).
    //      lane l holds agg[4c..4c+3], c = l&31 (duplicated halves). ----
    const float invN = 1.0f / 16.0f;
    float4 ag;
    {
        float4 a = make_float4(0.f, 0.f, 0.f, 0.f);
        #pragma unroll
        for (int t = 0; t < 8; ++t) {
            a.x += ov[t].x; a.y += ov[t].y; a.z += ov[t].z; a.w += ov[t].w;
        }
        a.x += __shfl_xor(a.x, 32);
        a.y += __shfl_xor(a.y, 32);
        a.z += __shfl_xor(a.z, 32);
        a.w += __shfl_xor(a.w, 32);
        ag = make_float4(a.x * invN, a.y * invN, a.z * invN, a.w * invN);
    }

    __syncthreads();   // sW1T4 (cross-wave) + sV1/sV2/sS visible (the ONLY barrier)

    // ---- mv1: h = relu(agg @ W1 + b1); R11-verified readlane mapping,
    //      conflict-free swizzled b128 weight reads. ----
    float a0 = b1v, a1 = 0.0f, a2 = 0.0f, a3 = 0.0f;
    #pragma unroll
    for (int d4 = 0; d4 < DIN / 4; ++d4) {
        const float4 w4 = sW1T4[l * 32 + (d4 ^ (l & 7))];
        a0 = fmaf(lane_bcast(ag.x, d4), w4.x, a0);   // agg[4d4]
        a1 = fmaf(lane_bcast(ag.y, d4), w4.y, a1);   // agg[4d4+1]
        a2 = fmaf(lane_bcast(ag.z, d4), w4.z, a2);   // agg[4d4+2]
        a3 = fmaf(lane_bcast(ag.w, d4), w4.w, a3);   // agg[4d4+3]
    }
    const float h = fmaxf((a0 + a1) + (a2 + a3), 0.0f);

    // ---- per-env scalars (R7/R8 trees) ----
    const float v1l  = sV1[l];
    const float v2l  = sV2[l];
    const float tb2u = sS[0];
    const float tb2w = sS[1];

    float t0 = h * v1l;
    float t1 = h * v2l;
    #pragma unroll
    for (int m = 32; m >= 1; m >>= 1) {
        t0 += __shfl_xor(t0, m);
        t1 += __shfl_xor(t1, m);
    }
    const float logit = t0 + tb2u;
    const float eV  = (logit > 0.0f) ? logit : 0.01f * logit;   // leaky slope 0.01
    const float wgt = 1.0f / (1.0f + expf(-eV));
    const float c   = t1 + tb2w + bvv;
    const float Sv  = fpv - wgt * fqv;

    // ---- outputs: 16 distinct x per env, broadcast over d; w scalar ----
    const int j0 = (4 * l) & 15;          // 0,4,8,12; j0..j0+3 never wrap
    float4 xo, wo;
    xo.x = fmaf(wgt, sDv[w][j0 + 0], Sv) * invN + c;
    xo.y = fmaf(wgt, sDv[w][j0 + 1], Sv) * invN + c;
    xo.z = fmaf(wgt, sDv[w][j0 + 2], Sv) * invN + c;
    xo.w = fmaf(wgt, sDv[w][j0 + 3], Sv) * invN + c;
    wo.x = wo.y = wo.z = wo.w = wgt;

    const size_t base = (size_t)e * (NN * NN) + 4 * l;
    *reinterpret_cast<float4*>(out_x + base) = xo;
    *reinterpret_cast<float4*>(out_w + base) = wo;
}

extern "C" void kernel_launch(void* const* d_in, const int* in_sizes, int n_in,
                              void* d_out, int out_size, void* d_ws, size_t ws_size,
                              hipStream_t stream) {
    const float* obs      = (const float*)d_in[0];
    const float* policies = (const float*)d_in[1];
    const float* actions  = (const float*)d_in[2];
    const float* W1       = (const float*)d_in[3];
    const float* b1       = (const float*)d_in[4];
    const float* W2       = (const float*)d_in[5];
    const float* b2       = (const float*)d_in[6];
    const float* Wfc      = (const float*)d_in[7];
    const float* Wattn    = (const float*)d_in[8];
    const float* Wv       = (const float*)d_in[9];
    const float* bv       = (const float*)d_in[10];

    float* out_x = (float*)d_out;                    // [B*N*N] = 1048576
    float* out_w = out_x + (size_t)BB * NN * NN;     // second tuple element

    critic_kernel<<<BB / GENV, NTHR, 0, stream>>>(obs, policies, actions,
                                                  W1, b1, W2, b2, Wfc, Wattn, Wv, bv,
                                                  out_x, out_w);
}